// Round 7
// baseline (746.115 us; speedup 1.0000x reference)
//
#include <hip/hip_runtime.h>
#include <math.h>

#define B 16
#define C 256
#define H 128
#define W 128
#define HW (H * W)      // 16384
#define HW4 (HW / 4)    // 4096 float4 chunks per image plane

// Spin tail: same tick count in both kernels; durations subtract to give the
// reduce's true time independent of the (unknown) wall-clock tick rate.
#define PROBE_TICKS 20000LL   // ~200 us if 100 MHz ref clock

typedef float vfloat4 __attribute__((ext_vector_type(4)));

__device__ __forceinline__ void spin_tail(long long ticks) {
  const long long t0 = wall_clock64();
  while (wall_clock64() - t0 < ticks) { }
}

// ---------------------------------------------------------------------------
// PROBE ROUND 2 (observability; revert tail next round).
// Kernel 1 = EXACT round-0 structure (345us best: nt loads, 1024x256 grid,
// launch_bounds(256,4)) + spin tail. Its FETCH_SIZE / WRITE_SIZE / Occupancy
// become visible in the top-5 table for the first time.
// ---------------------------------------------------------------------------
__global__ __launch_bounds__(256, 4) void reduce_mean_max(
    const float* __restrict__ x, float* __restrict__ feat) {
  const int t    = threadIdx.x;
  const int lane = t & 63;
  const int cq   = t >> 6;                       // wave id = channel quarter
  const int chunk = blockIdx.x * 64 + lane;      // [0, 65536)
  const int b    = chunk >> 12;                  // 4096 chunks per image
  const int s4   = chunk & (HW4 - 1);

  const vfloat4* xp = (const vfloat4*)x + (size_t)(b * C + cq * 64) * HW4 + s4;

  vfloat4 sum = (vfloat4)(0.f);
  vfloat4 mx  = (vfloat4)(-INFINITY);
#pragma unroll 8
  for (int c = 0; c < 64; ++c) {
    vfloat4 v = __builtin_nontemporal_load(&xp[(size_t)c * HW4]);
    sum += v;
    mx.x = fmaxf(mx.x, v.x); mx.y = fmaxf(mx.y, v.y);
    mx.z = fmaxf(mx.z, v.z); mx.w = fmaxf(mx.w, v.w);
  }

  __shared__ vfloat4 s_sum[4][64];
  __shared__ vfloat4 s_max[4][64];
  s_sum[cq][lane] = sum;
  s_max[cq][lane] = mx;
  __syncthreads();

  if (cq == 0) {
    vfloat4 a = s_sum[0][lane], b1 = s_sum[1][lane],
            c2 = s_sum[2][lane], d = s_sum[3][lane];
    const float inv = 1.0f / (float)C;
    vfloat4 mean = (a + b1 + c2 + d) * inv;
    ((vfloat4*)feat)[(size_t)(b * 2) * HW4 + s4] = mean;
  } else if (cq == 1) {
    vfloat4 a = s_max[0][lane], b1 = s_max[1][lane],
            c2 = s_max[2][lane], d = s_max[3][lane];
    vfloat4 m;
    m.x = fmaxf(fmaxf(a.x, b1.x), fmaxf(c2.x, d.x));
    m.y = fmaxf(fmaxf(a.y, b1.y), fmaxf(c2.y, d.y));
    m.z = fmaxf(fmaxf(a.z, b1.z), fmaxf(c2.z, d.z));
    m.w = fmaxf(fmaxf(a.w, b1.w), fmaxf(c2.w, d.w));
    ((vfloat4*)feat)[(size_t)(b * 2 + 1) * HW4 + s4] = m;
  }

  spin_tail(PROBE_TICKS);   // pure tail; memory-phase counters unpolluted
}

// ---------------------------------------------------------------------------
// Kernel 2: 3x3 conv + sigmoid (round-0 version, base ~5us) + SAME spin tail.
// Serves as the clock-rate calibration: R_reduce ~= dur(k1) - dur(k2) + 5us.
// ---------------------------------------------------------------------------
__global__ __launch_bounds__(256) void conv3x3_sigmoid(
    const float* __restrict__ feat, const float* __restrict__ wgt,
    float* __restrict__ out) {
  __shared__ float sw[18];
  if (threadIdx.x < 18) sw[threadIdx.x] = wgt[threadIdx.x];
  __syncthreads();

  const int idx = blockIdx.x * 256 + threadIdx.x;  // [0, 262144)
  const int b = idx >> 14;
  const int s = idx & (HW - 1);
  const int h = s >> 7;
  const int w = s & (W - 1);

  float acc = 0.f;
#pragma unroll
  for (int ci = 0; ci < 2; ++ci) {
    const float* f  = feat + (size_t)(b * 2 + ci) * HW;
    const float* kw = sw + ci * 9;
#pragma unroll
    for (int dh = -1; dh <= 1; ++dh) {
      const int hh = h + dh;
      if (hh < 0 || hh >= H) continue;
      const float* row = f + hh * W;
#pragma unroll
      for (int dw = -1; dw <= 1; ++dw) {
        const int ww = w + dw;
        if (ww < 0 || ww >= W) continue;
        acc += row[ww] * kw[(dh + 1) * 3 + (dw + 1)];
      }
    }
  }
  out[idx] = 1.f / (1.f + __expf(-acc));

  spin_tail(PROBE_TICKS);
}

extern "C" void kernel_launch(void* const* d_in, const int* in_sizes, int n_in,
                              void* d_out, int out_size, void* d_ws, size_t ws_size,
                              hipStream_t stream) {
  const float* x   = (const float*)d_in[0];   // [16, 256, 128, 128] fp32
  const float* wgt = (const float*)d_in[1];   // [1, 2, 3, 3] fp32
  float* out  = (float*)d_out;                // [16, 1, 128, 128] fp32
  float* feat = (float*)d_ws;                 // [16, 2, 128, 128] fp32 scratch

  reduce_mean_max<<<1024, 256, 0, stream>>>(x, feat);
  conv3x3_sigmoid<<<1024, 256, 0, stream>>>(feat, wgt, out);
}